// Round 3
// baseline (64529.724 us; speedup 1.0000x reference)
//
#include <hip/hip_runtime.h>
#include <stdint.h>
#include <stddef.h>

typedef uint32_t u32;

// ---------------- problem constants (fixed by reference file) ----------------
#define NB    256      // batch B
#define LFULL 412      // L
#define NCH   3        // C
#define CTX   336      // context_length
#define NSAMP 100      // n_samples
#define TM1   383      // T-1 (T = L - MAX_LAG = 384)
#define HID   64
#define NIN   15
#define RTOT  25600    // NB*NSAMP
#define NCTXS 8601600u // RTOT*CTX
#define NSTEP 47       // H-1

#define DROWS   20     // rows per persistent decode block
#define DBLOCKS (RTOT / DROWS)  // 1280 -> 5 exact block-generations per CU

#define JAX_PARTITIONABLE 1

__device__ const int c_LAGS[10] = {1,2,3,4,5,6,7,14,21,28};

// ---------------- threefry2x32 (matches jax._src.prng) ----------------
__host__ __device__ inline void tf2x32(u32 k0, u32 k1, u32 x0, u32 x1, u32& o0, u32& o1) {
  const u32 ks2 = k0 ^ k1 ^ 0x1BD11BDAu;
#define TFR(r) { x0 += x1; x1 = (x1 << (r)) | (x1 >> (32 - (r))); x1 ^= x0; }
  x0 += k0; x1 += k1;
  TFR(13) TFR(15) TFR(26) TFR(6)
  x0 += k1; x1 += ks2 + 1u;
  TFR(17) TFR(29) TFR(16) TFR(24)
  x0 += ks2; x1 += k0 + 2u;
  TFR(13) TFR(15) TFR(26) TFR(6)
  x0 += k0; x1 += k1 + 3u;
  TFR(17) TFR(29) TFR(16) TFR(24)
  x0 += k1; x1 += ks2 + 4u;
  TFR(13) TFR(15) TFR(26) TFR(6)
  x0 += ks2; x1 += k0 + 5u;
#undef TFR
  o0 = x0; o1 = x1;
}

__host__ __device__ inline u32 split_word_legacy(u32 k0, u32 k1, u32 n, u32 j) {
  u32 o0, o1;
  if (j < n) { tf2x32(k0, k1, j, n + j, o0, o1); return o0; }
  tf2x32(k0, k1, j - n, j, o0, o1); return o1;
}

__host__ __device__ inline void jx_subkey(u32 k0, u32 k1, u32 n, u32 i, u32& s0, u32& s1) {
#if JAX_PARTITIONABLE
  (void)n; tf2x32(k0, k1, 0u, i, s0, s1);
#else
  s0 = split_word_legacy(k0, k1, n, 2u * i);
  s1 = split_word_legacy(k0, k1, n, 2u * i + 1u);
#endif
}

__device__ inline u32 jx_bits(u32 k0, u32 k1, u32 n, u32 i) {
#if JAX_PARTITIONABLE
  (void)n; u32 o0, o1; tf2x32(k0, k1, 0u, i, o0, o1); return o0 ^ o1;
#else
  u32 o0, o1;
  if (n == 1u) { tf2x32(k0, k1, 0u, 0u, o0, o1); return o0; }
  const u32 h = n >> 1;
  if (i < h) { tf2x32(k0, k1, i, h + i, o0, o1); return o0; }
  tf2x32(k0, k1, i - h, i, o0, o1); return o1;
#endif
}

// ---------------- JAX-exact float transforms ----------------
__device__ inline float jax_erfinv(float x) {
#pragma clang fp contract(off)
  float w = -log1pf(-x * x);
  float p;
  if (w < 5.0f) {
    w = w - 2.5f;
    p = 2.81022636e-08f;
    p = 3.43273939e-07f + p * w;
    p = -3.5233877e-06f + p * w;
    p = -4.39150654e-06f + p * w;
    p = 0.00021858087f + p * w;
    p = -0.00125372503f + p * w;
    p = -0.00417768164f + p * w;
    p = 0.246640727f + p * w;
    p = 1.50140941f + p * w;
  } else {
    w = sqrtf(w) - 3.0f;
    p = -0.000200214257f;
    p = 0.000100950558f + p * w;
    p = 0.00134934322f + p * w;
    p = -0.00367342844f + p * w;
    p = 0.00573950773f + p * w;
    p = -0.0076224613f + p * w;
    p = 0.00943887047f + p * w;
    p = 1.00167406f + p * w;
    p = 2.83297682f + p * w;
  }
  return p * x;
}

__device__ inline float u01_from_bits(u32 bits) {
  return __uint_as_float((bits >> 9) | 0x3f800000u) - 1.0f;
}

__device__ inline float normal_from_bits(u32 bits) {
#pragma clang fp contract(off)
  const float lo = -0.99999994f;
  const float u = u01_from_bits(bits);
  float r = u * 2.0f + lo;
  r = fmaxf(lo, r);
  return 1.41421356f * jax_erfinv(r);
}

__device__ float jax_gamma_one(u32 k0, u32 k1, float alpha) {
#pragma clang fp contract(off)
  const bool boost_mask = (alpha >= 1.0f);
  const float alpha_orig = alpha;
  const float a = boost_mask ? alpha : (alpha + 1.0f);
  const float d = a - 0.33333334f;
  const float c = 0.33333334f / sqrtf(d);
  u32 K0, K1, S0, S1;
  jx_subkey(k0, k1, 2u, 0u, K0, K1);
  jx_subkey(k0, k1, 2u, 1u, S0, S1);
  float u_boost = 1.0f;
  if (!boost_mask) u_boost = u01_from_bits(jx_bits(S0, S1, 1u, 0u));
  float X = 0.0f, V = 1.0f, U = 2.0f;
  while (true) {
    if (!(U >= 1.0f - 0.0331f * (X * X))) break;
    if (!(logf(U) >= 0.5f * X + d * ((1.0f - V) + logf(V)))) break;
    u32 nk0, nk1, xk0, xk1, uk0, uk1;
    jx_subkey(K0, K1, 3u, 0u, nk0, nk1);
    jx_subkey(K0, K1, 3u, 1u, xk0, xk1);
    jx_subkey(K0, K1, 3u, 2u, uk0, uk1);
    K0 = nk0; K1 = nk1;
    float x, v;
    u32 c0 = xk0, c1 = xk1;
    do {
      u32 t0, t1, s0, s1;
      jx_subkey(c0, c1, 2u, 0u, t0, t1);
      jx_subkey(c0, c1, 2u, 1u, s0, s1);
      c0 = t0; c1 = t1;
      x = normal_from_bits(jx_bits(s0, s1, 1u, 0u));
      v = 1.0f + x * c;
    } while (v <= 0.0f);
    X = x * x;
    V = (v * v) * v;
    U = u01_from_bits(jx_bits(uk0, uk1, 1u, 0u));
  }
  const float sample = d * V;
  const float boost = boost_mask ? 1.0f : powf(u_boost, 1.0f / alpha_orig);
  return sample * boost;
}

__device__ inline float sigm(float x) { return 1.0f / (1.0f + expf(-x)); }
__device__ inline float softplusf(float x) { return fmaxf(x, 0.0f) + log1pf(expf(-fabsf(x))); }

// ---------------- workspace layout (floats) ----------------
enum : size_t {
  OFF_INP  = 0,
  OFF_CT   = OFF_INP + (size_t)NB * TM1 * NIN,
  OFF_TS   = OFF_CT + (size_t)NB * CTX,
  OFF_LTS  = OFF_TS + NB,
  OFF_DF   = OFF_LTS + NB,
  OFF_LOC  = OFF_DF + (size_t)NB * CTX,
  OFF_SC   = OFF_LOC + (size_t)NB * CTX,
  OFF_H0F  = OFF_SC + (size_t)NB * CTX,
  OFF_C0F  = OFF_H0F + (size_t)NB * HID,
  OFF_H1F  = OFF_C0F + (size_t)NB * HID,
  OFF_C1F  = OFF_H1F + (size_t)NB * HID,
  OFF_YH   = OFF_C1F + (size_t)NB * HID,
  WS_FLOATS = OFF_YH + (size_t)RTOT * TM1
};

// ---------------- kernel 1: tscale + feature build ----------------
__global__ void __launch_bounds__(256) prep_kernel(
    const float* __restrict__ X, const float* __restrict__ emb,
    float* __restrict__ inp, float* __restrict__ ct,
    float* __restrict__ tscale, float* __restrict__ ltscale)
{
  const int b = blockIdx.x, t = threadIdx.x;
  __shared__ float red[256];
  __shared__ float ts_sh;
  const float* Xb = X + (size_t)b * LFULL * NCH;
  float p = fabsf(Xb[(28 + t) * NCH]);
  if (t < 80) p += fabsf(Xb[(28 + 256 + t) * NCH]);
  red[t] = p;
  for (int st = 128; st > 0; st >>= 1) { __syncthreads(); if (t < st) red[t] += red[t + st]; }
  __syncthreads();
  if (t == 0) {
    float ts = red[0] / 336.0f;
    ts = fmaxf(ts, 1e-10f);
    tscale[b] = ts; ltscale[b] = logf(ts); ts_sh = ts;
  }
  __syncthreads();
  const float ts = ts_sh;
  const float lts = logf(ts);
  const float ev = emb[0];
  for (int idx = t; idx < TM1 * NIN; idx += 256) {
    const int tt = idx / NIN, f = idx - tt * NIN;
    float val;
    if (f == 0)       val = (tt < CTX) ? Xb[(28 + tt) * NCH] / ts : 0.0f;
    else if (f <= 10) val = (tt < CTX) ? Xb[(28 + tt - c_LAGS[f - 1]) * NCH] / ts : 0.0f;
    else if (f == 11) val = ev;
    else if (f == 12) val = Xb[(28 + tt) * NCH + 2];
    else if (f == 13) val = lts;
    else              val = Xb[(28 + tt) * NCH + 1];
    inp[(size_t)(b * TM1 + tt) * NIN + f] = val;
    if (f == 0 && tt < CTX) ct[b * CTX + tt] = val;
  }
}

// ---------------- kernel 2: fused 2-layer context LSTM + head ----------------
__global__ void __launch_bounds__(256) ctx_lstm_kernel(
    const float* __restrict__ inp,
    const float* __restrict__ Wih0, const float* __restrict__ Whh0,
    const float* __restrict__ bih0, const float* __restrict__ bhh0,
    const float* __restrict__ Wih1, const float* __restrict__ Whh1,
    const float* __restrict__ bih1, const float* __restrict__ bhh1,
    const float* __restrict__ wdf, const float* __restrict__ bdfp,
    const float* __restrict__ wloc, const float* __restrict__ blocp,
    const float* __restrict__ wsc, const float* __restrict__ bscp,
    float* __restrict__ dfo, float* __restrict__ loco, float* __restrict__ sco,
    float* __restrict__ h0f, float* __restrict__ c0f,
    float* __restrict__ h1f, float* __restrict__ c1f)
{
  const int b = blockIdx.x, t = threadIdx.x;
  __shared__ float x_s[16], h0_s[64], h1_s[64], g_s[256];
  float wih0[15], whh0[64], wih1[64], whh1[64];
#pragma unroll
  for (int k = 0; k < 15; k++) wih0[k] = Wih0[t * 15 + k];
#pragma unroll
  for (int k = 0; k < 64; k++) whh0[k] = Whh0[t * 64 + k];
#pragma unroll
  for (int k = 0; k < 64; k++) wih1[k] = Wih1[t * 64 + k];
#pragma unroll
  for (int k = 0; k < 64; k++) whh1[k] = Whh1[t * 64 + k];
  const float bi0 = bih0[t], bh0 = bhh0[t], bi1 = bih1[t], bh1 = bhh1[t];
  const float bdf = bdfp[0], bloc = blocp[0], bsc = bscp[0];
  float wdfv = 0.f, wlocv = 0.f, wscv = 0.f;
  float c0 = 0.f, h0 = 0.f, c1 = 0.f, h1 = 0.f;
  if (t < 64) { h0_s[t] = 0.f; h1_s[t] = 0.f; wdfv = wdf[t]; wlocv = wloc[t]; wscv = wsc[t]; }
  __syncthreads();
  for (int tt = 0; tt < CTX; tt++) {
    if (t < 15) x_s[t] = inp[(size_t)(b * TM1 + tt) * NIN + t];
    __syncthreads();
    {
      float a = 0.f;
#pragma unroll
      for (int k = 0; k < 15; k++) a += wih0[k] * x_s[k];
      a += bi0;
      float a2 = 0.f;
#pragma unroll
      for (int k = 0; k < 64; k++) a2 += whh0[k] * h0_s[k];
      g_s[t] = (a + a2) + bh0;
    }
    __syncthreads();
    if (t < 64) {
      const float gi = g_s[t], gf = g_s[64 + t], gg = g_s[128 + t], go = g_s[192 + t];
      c0 = sigm(gf) * c0 + sigm(gi) * tanhf(gg);
      h0 = sigm(go) * tanhf(c0);
      h0_s[t] = h0;
    }
    __syncthreads();
    {
      float a = 0.f;
#pragma unroll
      for (int k = 0; k < 64; k++) a += wih1[k] * h0_s[k];
      a += bi1;
      float a2 = 0.f;
#pragma unroll
      for (int k = 0; k < 64; k++) a2 += whh1[k] * h1_s[k];
      g_s[t] = (a + a2) + bh1;
    }
    __syncthreads();
    if (t < 64) {
      const float gi = g_s[t], gf = g_s[64 + t], gg = g_s[128 + t], go = g_s[192 + t];
      c1 = sigm(gf) * c1 + sigm(gi) * tanhf(gg);
      h1 = sigm(go) * tanhf(c1);
      h1_s[t] = h1;
      float pd = h1 * wdfv, pl = h1 * wlocv, ps = h1 * wscv;
#pragma unroll
      for (int off = 32; off > 0; off >>= 1) {
        pd += __shfl_down(pd, off, 64);
        pl += __shfl_down(pl, off, 64);
        ps += __shfl_down(ps, off, 64);
      }
      if (t == 0) {
        dfo[b * CTX + tt]  = 2.0f + softplusf(pd + bdf);
        loco[b * CTX + tt] = pl + bloc;
        sco[b * CTX + tt]  = softplusf(ps + bsc);
      }
    }
    __syncthreads();
  }
  if (t < 64) { h0f[b * 64 + t] = h0; c0f[b * 64 + t] = c0; h1f[b * 64 + t] = h1; c1f[b * 64 + t] = c1; }
}

// ---------------- kernel 3: context sampling (y_ctx) ----------------
__global__ void __launch_bounds__(256) ctx_sample_kernel(
    const float* __restrict__ df, const float* __restrict__ loc, const float* __restrict__ sc,
    const float* __restrict__ tscale, float* __restrict__ yhat,
    u32 kz0, u32 kz1, u32 kg0, u32 kg1)
{
  const int i = blockIdx.x * 256 + threadIdx.x;
  const int r = i / CTX, t = i - r * CTX;
  const int b = r / NSAMP;
  const float dfv = df[b * CTX + t], lv = loc[b * CTX + t], sv = sc[b * CTX + t];
  const float z = normal_from_bits(jx_bits(kz0, kz1, NCTXS, (u32)i));
  u32 gk0, gk1;
  jx_subkey(kg0, kg1, NCTXS, (u32)i, gk0, gk1);
  const float g = jax_gamma_one(gk0, gk1, dfv * 0.5f);
  const float y = (lv + sv * (z * sqrtf(dfv / (2.0f * g)))) * tscale[b];
  yhat[(size_t)r * TM1 + t] = y;
}

// ---------------- kernel 5: persistent decode (all 47 steps in one launch) --
// 1280 blocks x 20 rows x 512 threads. Per-thread weights K-half split (104
// floats). h0/h1/lag-ring in LDS, c0/c1 in registers; rows independent
// across steps so no inter-block sync is needed.
#define DEC_GROUP(G0, GCNT, C0O, C1O)                                          \
  {                                                                            \
    if (t < 128) {                                                             \
      const int i = t >> 4, f = t & 15;                                        \
      if (i < (GCNT)) {                                                        \
        const int row = (G0) + i;                                              \
        const int bb = (base + row) / NSAMP;                                   \
        if (f == 0) { const float nsv = prevs[row] / tsr[row];                 \
          xs[i][0] = nsv; hist[row][s & 63] = nsv; }                           \
        else if (f <= 10) xs[i][f] = hist[row][(s - c_LAGS[f - 1]) & 63];      \
        else if (f < 15) xs[i][f] = inp[((size_t)bb * TM1 + CTX + s) * NIN + f]; \
        else xs[i][15] = 0.0f;                                                 \
      }                                                                        \
    }                                                                          \
    __syncthreads();                                                           \
    { float acc[GCNT];                                                         \
      _Pragma("unroll")                                                        \
      for (int i = 0; i < (GCNT); i++) {                                       \
        float a = 0.f;                                                         \
        const float* xp = &xs[i][hf * 8];                                      \
        _Pragma("unroll")                                                      \
        for (int k = 0; k < 8; k++) a += wih0h[k] * xp[k];                     \
        const float4* hp = (const float4*)&h0s[(G0) + i][hf * 32];             \
        _Pragma("unroll")                                                      \
        for (int k = 0; k < 8; k++) { float4 v = hp[k];                        \
          a += whh0h[4*k]*v.x; a += whh0h[4*k+1]*v.y;                          \
          a += whh0h[4*k+2]*v.z; a += whh0h[4*k+3]*v.w; }                      \
        acc[i] = a; }                                                          \
      _Pragma("unroll")                                                        \
      for (int i = 0; i < (GCNT); i++) {                                       \
        if (hf) gB[i][g] = acc[i]; else gA[i][g] = acc[i]; } }                 \
    __syncthreads();                                                           \
    if (w < (GCNT)) {                                                          \
      const int row = (G0) + w;                                                \
      const float gi = (gA[w][j]       + gB[w][j])       + bs00;               \
      const float gf = (gA[w][64 + j]  + gB[w][64 + j])  + bs01;               \
      const float gg = (gA[w][128 + j] + gB[w][128 + j]) + bs02;               \
      const float go = (gA[w][192 + j] + gB[w][192 + j]) + bs03;               \
      C0O = sigm(gf) * C0O + sigm(gi) * tanhf(gg);                             \
      h0s[row][j] = sigm(go) * tanhf(C0O);                                     \
    }                                                                          \
    __syncthreads();                                                           \
    { float acc[GCNT];                                                         \
      _Pragma("unroll")                                                        \
      for (int i = 0; i < (GCNT); i++) {                                       \
        float a = 0.f;                                                         \
        const float4* hp = (const float4*)&h0s[(G0) + i][hf * 32];             \
        _Pragma("unroll")                                                      \
        for (int k = 0; k < 8; k++) { float4 v = hp[k];                        \
          a += wih1h[4*k]*v.x; a += wih1h[4*k+1]*v.y;                          \
          a += wih1h[4*k+2]*v.z; a += wih1h[4*k+3]*v.w; }                      \
        const float4* qp = (const float4*)&h1s[(G0) + i][hf * 32];             \
        _Pragma("unroll")                                                      \
        for (int k = 0; k < 8; k++) { float4 v = qp[k];                        \
          a += whh1h[4*k]*v.x; a += whh1h[4*k+1]*v.y;                          \
          a += whh1h[4*k+2]*v.z; a += whh1h[4*k+3]*v.w; }                      \
        acc[i] = a; }                                                          \
      _Pragma("unroll")                                                        \
      for (int i = 0; i < (GCNT); i++) {                                       \
        if (hf) gB[i][g] = acc[i]; else gA[i][g] = acc[i]; } }                 \
    __syncthreads();                                                           \
    if (w < (GCNT)) {                                                          \
      const int row = (G0) + w;                                                \
      const float gi = (gA[w][j]       + gB[w][j])       + bs10;               \
      const float gf = (gA[w][64 + j]  + gB[w][64 + j])  + bs11;               \
      const float gg = (gA[w][128 + j] + gB[w][128 + j]) + bs12;               \
      const float go = (gA[w][192 + j] + gB[w][192 + j]) + bs13;               \
      C1O = sigm(gf) * C1O + sigm(gi) * tanhf(gg);                             \
      const float h1v = sigm(go) * tanhf(C1O);                                 \
      h1s[row][j] = h1v;                                                       \
      float pd = h1v * wdfv, pl = h1v * wlocv, ps = h1v * wscv;                \
      _Pragma("unroll")                                                        \
      for (int off = 32; off > 0; off >>= 1) {                                 \
        pd += __shfl_down(pd, off, 64);                                        \
        pl += __shfl_down(pl, off, 64);                                        \
        ps += __shfl_down(ps, off, 64); }                                      \
      if (j == 0) { dfL[row] = 2.0f + softplusf(pd + bdf);                     \
        locL[row] = pl + bloc; scL[row] = softplusf(ps + bsc); }               \
    }                                                                          \
    __syncthreads();                                                           \
  }

__global__ void __launch_bounds__(512, 1) dec_persist_kernel(
    const float* __restrict__ inp, const float* __restrict__ tscale,
    const float* __restrict__ Wih0, const float* __restrict__ Whh0,
    const float* __restrict__ bih0, const float* __restrict__ bhh0,
    const float* __restrict__ Wih1, const float* __restrict__ Whh1,
    const float* __restrict__ bih1, const float* __restrict__ bhh1,
    const float* __restrict__ wdf, const float* __restrict__ bdfp,
    const float* __restrict__ wloc, const float* __restrict__ blocp,
    const float* __restrict__ wsc, const float* __restrict__ bscp,
    const float* __restrict__ h0f, const float* __restrict__ c0f,
    const float* __restrict__ h1f, const float* __restrict__ c1f,
    const float* __restrict__ ct, float* __restrict__ yhat,
    u32 kl0, u32 kl1)
{
  const int t  = threadIdx.x;
  const int g  = t & 255;      // gate index
  const int hf = t >> 8;       // K-half (0/1)
  const int w  = t >> 6;       // wave within block (0..7)
  const int j  = t & 63;       // lane / hidden unit

  __shared__ __align__(16) float h0s[DROWS][64];
  __shared__ __align__(16) float h1s[DROWS][64];
  __shared__ __align__(16) float hist[DROWS][64];   // lag ring buffer
  __shared__ __align__(16) float gA[8][256];
  __shared__ __align__(16) float gB[8][256];
  __shared__ __align__(16) float xs[8][16];
  __shared__ float prevs[DROWS], tsr[DROWS];
  __shared__ float dfL[DROWS], locL[DROWS], scL[DROWS];

  const int base = blockIdx.x * DROWS;

  // ---- per-thread weights: K-half split (104 floats) ----
  float wih0h[8], whh0h[32], wih1h[32], whh1h[32];
#pragma unroll
  for (int k = 0; k < 8; k++) {
    if (hf == 0) wih0h[k] = Wih0[g * 15 + k];
    else         wih0h[k] = (k < 7) ? Wih0[g * 15 + 8 + k] : 0.0f;
  }
  {
    const float4* W = (const float4*)(Whh0 + g * 64 + hf * 32);
#pragma unroll
    for (int k = 0; k < 8; k++) { float4 v = W[k]; whh0h[4*k]=v.x; whh0h[4*k+1]=v.y; whh0h[4*k+2]=v.z; whh0h[4*k+3]=v.w; }
  }
  {
    const float4* W = (const float4*)(Wih1 + g * 64 + hf * 32);
#pragma unroll
    for (int k = 0; k < 8; k++) { float4 v = W[k]; wih1h[4*k]=v.x; wih1h[4*k+1]=v.y; wih1h[4*k+2]=v.z; wih1h[4*k+3]=v.w; }
  }
  {
    const float4* W = (const float4*)(Whh1 + g * 64 + hf * 32);
#pragma unroll
    for (int k = 0; k < 8; k++) { float4 v = W[k]; whh1h[4*k]=v.x; whh1h[4*k+1]=v.y; whh1h[4*k+2]=v.z; whh1h[4*k+3]=v.w; }
  }
  // bias sums per elementwise lane j (gate positions j, 64+j, 128+j, 192+j)
  const float bs00 = bih0[j]       + bhh0[j];
  const float bs01 = bih0[64 + j]  + bhh0[64 + j];
  const float bs02 = bih0[128 + j] + bhh0[128 + j];
  const float bs03 = bih0[192 + j] + bhh0[192 + j];
  const float bs10 = bih1[j]       + bhh1[j];
  const float bs11 = bih1[64 + j]  + bhh1[64 + j];
  const float bs12 = bih1[128 + j] + bhh1[128 + j];
  const float bs13 = bih1[192 + j] + bhh1[192 + j];
  const float bdf = bdfp[0], bloc = blocp[0], bsc = bscp[0];
  const float wdfv = wdf[j], wlocv = wloc[j], wscv = wsc[j];

  // ---- state init ----
  for (int idx = t; idx < DROWS * 64; idx += 512) {
    const int i = idx >> 6, jj = idx & 63;
    const int bb = (base + i) / NSAMP;
    h0s[i][jj] = h0f[bb * 64 + jj];
    h1s[i][jj] = h1f[bb * 64 + jj];
  }
  for (int idx = t; idx < DROWS * 28; idx += 512) {
    const int i = idx / 28, k = idx - i * 28;
    const int bb = (base + i) / NSAMP;
    hist[i][63 - k] = ct[bb * CTX + 335 - k];   // past_target[:, k]
  }
  if (t < DROWS) {
    const int rg = base + t;
    const int bb = rg / NSAMP;
    prevs[t] = yhat[(size_t)rg * TM1 + 335];
    tsr[t] = tscale[bb];
  }
  float c0a = 0.f, c1a = 0.f, c0b = 0.f, c1b = 0.f, c0c = 0.f, c1c = 0.f;
  {
    const int bb = (base + w) / NSAMP;
    c0a = c0f[bb * 64 + j]; c1a = c1f[bb * 64 + j];
  }
  {
    const int bb = (base + 8 + w) / NSAMP;
    c0b = c0f[bb * 64 + j]; c1b = c1f[bb * 64 + j];
  }
  if (16 + w < DROWS) {
    const int bb = (base + 16 + w) / NSAMP;
    c0c = c0f[bb * 64 + j]; c1c = c1f[bb * 64 + j];
  }
  __syncthreads();

  // ---- step loop ----
  for (int s = 0; s < NSTEP; s++) {
    DEC_GROUP(0, 8, c0a, c1a)
    DEC_GROUP(8, 8, c0b, c1b)
    DEC_GROUP(16, 4, c0c, c1c)

    // sampling for all 20 rows
    if (t < DROWS) {
      const int row = t, rg = base + row;
      u32 ks0, ks1, skz0, skz1, skg0, skg1;
      tf2x32(kl0, kl1, 0u, (u32)s, ks0, ks1);     // keys[s]
      tf2x32(ks0, ks1, 0u, 0u, skz0, skz1);
      tf2x32(ks0, ks1, 0u, 1u, skg0, skg1);
      const float dfv = dfL[row], lv = locL[row], scv = scL[row];
      const float z = normal_from_bits(jx_bits(skz0, skz1, RTOT, (u32)rg));
      u32 gk0, gk1;
      jx_subkey(skg0, skg1, RTOT, (u32)rg, gk0, gk1);
      const float gam = jax_gamma_one(gk0, gk1, dfv * 0.5f);
      const float y = (lv + scv * (z * sqrtf(dfv / (2.0f * gam)))) * tsr[row];
      yhat[(size_t)rg * TM1 + CTX + s] = y;
      prevs[row] = y;
    }
    __syncthreads();
  }
}

// ---------------- kernel 6: median over 100 samples per (b,t) ----------------
__global__ void __launch_bounds__(256) median_kernel(
    const float* __restrict__ yhat, float* __restrict__ out)
{
  __shared__ float vals[4][100];
  const int wave = threadIdx.x >> 6, lane = threadIdx.x & 63;
  const int cell = blockIdx.x * 4 + wave;
  const int b = cell / TM1, t = cell - b * TM1;
  const float* basep = yhat + (size_t)b * NSAMP * TM1 + t;
  const float v1 = basep[(size_t)lane * TM1];
  vals[wave][lane] = v1;
  float v2 = 0.f;
  if (lane < 36) { v2 = basep[(size_t)(64 + lane) * TM1]; vals[wave][64 + lane] = v2; }
  __syncthreads();
  int cl1 = 0, ce1 = 0, cl2 = 0, ce2 = 0;
  for (int jj = 0; jj < 100; jj++) {
    const float w = vals[wave][jj];
    cl1 += (w < v1); ce1 += (w == v1);
    cl2 += (w < v2); ce2 += (w == v2);
  }
  if (cl1 <= 49 && 49 < cl1 + ce1) out[cell] = v1;
  if (lane < 36 && cl2 <= 49 && 49 < cl2 + ce2) out[cell] = v2;
}

// ---------------- launch ----------------
extern "C" void kernel_launch(void* const* d_in, const int* in_sizes, int n_in,
                              void* d_out, int out_size, void* d_ws, size_t ws_size,
                              hipStream_t stream) {
  (void)in_sizes; (void)n_in; (void)out_size; (void)ws_size;
  const float* X     = (const float*)d_in[0];
  const float* Wih0  = (const float*)d_in[2];
  const float* Whh0  = (const float*)d_in[3];
  const float* bih0  = (const float*)d_in[4];
  const float* bhh0  = (const float*)d_in[5];
  const float* Wih1  = (const float*)d_in[6];
  const float* Whh1  = (const float*)d_in[7];
  const float* bih1  = (const float*)d_in[8];
  const float* bhh1  = (const float*)d_in[9];
  const float* wdf   = (const float*)d_in[10];
  const float* bdf   = (const float*)d_in[11];
  const float* wloc  = (const float*)d_in[12];
  const float* bloc  = (const float*)d_in[13];
  const float* wsc   = (const float*)d_in[14];
  const float* bsc   = (const float*)d_in[15];
  const float* emb   = (const float*)d_in[16];

  float* wsf = (float*)d_ws;
  float* inp  = wsf + OFF_INP;
  float* ct   = wsf + OFF_CT;
  float* ts   = wsf + OFF_TS;
  float* lts  = wsf + OFF_LTS;
  float* dfp  = wsf + OFF_DF;
  float* locp = wsf + OFF_LOC;
  float* scp  = wsf + OFF_SC;
  float* h0f  = wsf + OFF_H0F;
  float* c0f  = wsf + OFF_C0F;
  float* h1f  = wsf + OFF_H1F;
  float* c1f  = wsf + OFF_C1F;
  float* yhat = wsf + OFF_YH;

  const u32 key0 = 0u, key1 = 42u;
  u32 kc0, kc1, kl0, kl1;
  jx_subkey(key0, key1, 2u, 0u, kc0, kc1);
  jx_subkey(key0, key1, 2u, 1u, kl0, kl1);
  u32 kz0, kz1, kg0, kg1;
  jx_subkey(kc0, kc1, 2u, 0u, kz0, kz1);
  jx_subkey(kc0, kc1, 2u, 1u, kg0, kg1);

  prep_kernel<<<NB, 256, 0, stream>>>(X, emb, inp, ct, ts, lts);
  ctx_lstm_kernel<<<NB, 256, 0, stream>>>(inp, Wih0, Whh0, bih0, bhh0, Wih1, Whh1, bih1, bhh1,
                                          wdf, bdf, wloc, bloc, wsc, bsc,
                                          dfp, locp, scp, h0f, c0f, h1f, c1f);
  ctx_sample_kernel<<<NCTXS / 256, 256, 0, stream>>>(dfp, locp, scp, ts, yhat, kz0, kz1, kg0, kg1);
  dec_persist_kernel<<<DBLOCKS, 512, 0, stream>>>(inp, ts, Wih0, Whh0, bih0, bhh0,
                                                  Wih1, Whh1, bih1, bhh1,
                                                  wdf, bdf, wloc, bloc, wsc, bsc,
                                                  h0f, c0f, h1f, c1f, ct, yhat, kl0, kl1);
  median_kernel<<<(NB * TM1) / 4, 256, 0, stream>>>(yhat, (float*)d_out);
}

// Round 4
// 62194.373 us; speedup vs baseline: 1.0375x; 1.0375x over previous
//
#include <hip/hip_runtime.h>
#include <stdint.h>
#include <stddef.h>

typedef uint32_t u32;

// ---------------- problem constants (fixed by reference file) ----------------
#define NB    256      // batch B
#define LFULL 412      // L
#define NCH   3        // C
#define CTX   336      // context_length
#define NSAMP 100      // n_samples
#define TM1   383      // T-1 (T = L - MAX_LAG = 384)
#define HID   64
#define NIN   15
#define RTOT  25600    // NB*NSAMP
#define NCTXS 8601600u // RTOT*CTX
#define NSTEP 47       // H-1

#define DROWS   16     // rows per persistent decode block
#define DBLOCKS (RTOT / DROWS)  // 1600

#define JAX_PARTITIONABLE 1

__device__ const int c_LAGS[10] = {1,2,3,4,5,6,7,14,21,28};

// ---------------- threefry2x32 (matches jax._src.prng) ----------------
__host__ __device__ inline void tf2x32(u32 k0, u32 k1, u32 x0, u32 x1, u32& o0, u32& o1) {
  const u32 ks2 = k0 ^ k1 ^ 0x1BD11BDAu;
#define TFR(r) { x0 += x1; x1 = (x1 << (r)) | (x1 >> (32 - (r))); x1 ^= x0; }
  x0 += k0; x1 += k1;
  TFR(13) TFR(15) TFR(26) TFR(6)
  x0 += k1; x1 += ks2 + 1u;
  TFR(17) TFR(29) TFR(16) TFR(24)
  x0 += ks2; x1 += k0 + 2u;
  TFR(13) TFR(15) TFR(26) TFR(6)
  x0 += k0; x1 += k1 + 3u;
  TFR(17) TFR(29) TFR(16) TFR(24)
  x0 += k1; x1 += ks2 + 4u;
  TFR(13) TFR(15) TFR(26) TFR(6)
  x0 += ks2; x1 += k0 + 5u;
#undef TFR
  o0 = x0; o1 = x1;
}

__host__ __device__ inline u32 split_word_legacy(u32 k0, u32 k1, u32 n, u32 j) {
  u32 o0, o1;
  if (j < n) { tf2x32(k0, k1, j, n + j, o0, o1); return o0; }
  tf2x32(k0, k1, j - n, j, o0, o1); return o1;
}

__host__ __device__ inline void jx_subkey(u32 k0, u32 k1, u32 n, u32 i, u32& s0, u32& s1) {
#if JAX_PARTITIONABLE
  (void)n; tf2x32(k0, k1, 0u, i, s0, s1);
#else
  s0 = split_word_legacy(k0, k1, n, 2u * i);
  s1 = split_word_legacy(k0, k1, n, 2u * i + 1u);
#endif
}

__device__ inline u32 jx_bits(u32 k0, u32 k1, u32 n, u32 i) {
#if JAX_PARTITIONABLE
  (void)n; u32 o0, o1; tf2x32(k0, k1, 0u, i, o0, o1); return o0 ^ o1;
#else
  u32 o0, o1;
  if (n == 1u) { tf2x32(k0, k1, 0u, 0u, o0, o1); return o0; }
  const u32 h = n >> 1;
  if (i < h) { tf2x32(k0, k1, i, h + i, o0, o1); return o0; }
  tf2x32(k0, k1, i - h, i, o0, o1); return o1;
#endif
}

// ---------------- JAX-exact float transforms ----------------
__device__ inline float jax_erfinv(float x) {
#pragma clang fp contract(off)
  float w = -log1pf(-x * x);
  float p;
  if (w < 5.0f) {
    w = w - 2.5f;
    p = 2.81022636e-08f;
    p = 3.43273939e-07f + p * w;
    p = -3.5233877e-06f + p * w;
    p = -4.39150654e-06f + p * w;
    p = 0.00021858087f + p * w;
    p = -0.00125372503f + p * w;
    p = -0.00417768164f + p * w;
    p = 0.246640727f + p * w;
    p = 1.50140941f + p * w;
  } else {
    w = sqrtf(w) - 3.0f;
    p = -0.000200214257f;
    p = 0.000100950558f + p * w;
    p = 0.00134934322f + p * w;
    p = -0.00367342844f + p * w;
    p = 0.00573950773f + p * w;
    p = -0.0076224613f + p * w;
    p = 0.00943887047f + p * w;
    p = 1.00167406f + p * w;
    p = 2.83297682f + p * w;
  }
  return p * x;
}

__device__ inline float u01_from_bits(u32 bits) {
  return __uint_as_float((bits >> 9) | 0x3f800000u) - 1.0f;
}

__device__ inline float normal_from_bits(u32 bits) {
#pragma clang fp contract(off)
  const float lo = -0.99999994f;
  const float u = u01_from_bits(bits);
  float r = u * 2.0f + lo;
  r = fmaxf(lo, r);
  return 1.41421356f * jax_erfinv(r);
}

__device__ float jax_gamma_one(u32 k0, u32 k1, float alpha) {
#pragma clang fp contract(off)
  const bool boost_mask = (alpha >= 1.0f);
  const float alpha_orig = alpha;
  const float a = boost_mask ? alpha : (alpha + 1.0f);
  const float d = a - 0.33333334f;
  const float c = 0.33333334f / sqrtf(d);
  u32 K0, K1, S0, S1;
  jx_subkey(k0, k1, 2u, 0u, K0, K1);
  jx_subkey(k0, k1, 2u, 1u, S0, S1);
  float u_boost = 1.0f;
  if (!boost_mask) u_boost = u01_from_bits(jx_bits(S0, S1, 1u, 0u));
  float X = 0.0f, V = 1.0f, U = 2.0f;
  while (true) {
    if (!(U >= 1.0f - 0.0331f * (X * X))) break;
    if (!(logf(U) >= 0.5f * X + d * ((1.0f - V) + logf(V)))) break;
    u32 nk0, nk1, xk0, xk1, uk0, uk1;
    jx_subkey(K0, K1, 3u, 0u, nk0, nk1);
    jx_subkey(K0, K1, 3u, 1u, xk0, xk1);
    jx_subkey(K0, K1, 3u, 2u, uk0, uk1);
    K0 = nk0; K1 = nk1;
    float x, v;
    u32 c0 = xk0, c1 = xk1;
    do {
      u32 t0, t1, s0, s1;
      jx_subkey(c0, c1, 2u, 0u, t0, t1);
      jx_subkey(c0, c1, 2u, 1u, s0, s1);
      c0 = t0; c1 = t1;
      x = normal_from_bits(jx_bits(s0, s1, 1u, 0u));
      v = 1.0f + x * c;
    } while (v <= 0.0f);
    X = x * x;
    V = (v * v) * v;
    U = u01_from_bits(jx_bits(uk0, uk1, 1u, 0u));
  }
  const float sample = d * V;
  const float boost = boost_mask ? 1.0f : powf(u_boost, 1.0f / alpha_orig);
  return sample * boost;
}

__device__ inline float sigm(float x) { return 1.0f / (1.0f + expf(-x)); }
__device__ inline float softplusf(float x) { return fmaxf(x, 0.0f) + log1pf(expf(-fabsf(x))); }

// ---------------- workspace layout (floats) ----------------
enum : size_t {
  OFF_INP  = 0,
  OFF_CT   = OFF_INP + (size_t)NB * TM1 * NIN,
  OFF_TS   = OFF_CT + (size_t)NB * CTX,
  OFF_LTS  = OFF_TS + NB,
  OFF_DF   = OFF_LTS + NB,
  OFF_LOC  = OFF_DF + (size_t)NB * CTX,
  OFF_SC   = OFF_LOC + (size_t)NB * CTX,
  OFF_H0F  = OFF_SC + (size_t)NB * CTX,
  OFF_C0F  = OFF_H0F + (size_t)NB * HID,
  OFF_H1F  = OFF_C0F + (size_t)NB * HID,
  OFF_C1F  = OFF_H1F + (size_t)NB * HID,
  OFF_YH   = OFF_C1F + (size_t)NB * HID,
  WS_FLOATS = OFF_YH + (size_t)RTOT * TM1
};

// ---------------- kernel 1: tscale + feature build ----------------
__global__ void __launch_bounds__(256) prep_kernel(
    const float* __restrict__ X, const float* __restrict__ emb,
    float* __restrict__ inp, float* __restrict__ ct,
    float* __restrict__ tscale, float* __restrict__ ltscale)
{
  const int b = blockIdx.x, t = threadIdx.x;
  __shared__ float red[256];
  __shared__ float ts_sh;
  const float* Xb = X + (size_t)b * LFULL * NCH;
  float p = fabsf(Xb[(28 + t) * NCH]);
  if (t < 80) p += fabsf(Xb[(28 + 256 + t) * NCH]);
  red[t] = p;
  for (int st = 128; st > 0; st >>= 1) { __syncthreads(); if (t < st) red[t] += red[t + st]; }
  __syncthreads();
  if (t == 0) {
    float ts = red[0] / 336.0f;
    ts = fmaxf(ts, 1e-10f);
    tscale[b] = ts; ltscale[b] = logf(ts); ts_sh = ts;
  }
  __syncthreads();
  const float ts = ts_sh;
  const float lts = logf(ts);
  const float ev = emb[0];
  for (int idx = t; idx < TM1 * NIN; idx += 256) {
    const int tt = idx / NIN, f = idx - tt * NIN;
    float val;
    if (f == 0)       val = (tt < CTX) ? Xb[(28 + tt) * NCH] / ts : 0.0f;
    else if (f <= 10) val = (tt < CTX) ? Xb[(28 + tt - c_LAGS[f - 1]) * NCH] / ts : 0.0f;
    else if (f == 11) val = ev;
    else if (f == 12) val = Xb[(28 + tt) * NCH + 2];
    else if (f == 13) val = lts;
    else              val = Xb[(28 + tt) * NCH + 1];
    inp[(size_t)(b * TM1 + tt) * NIN + f] = val;
    if (f == 0 && tt < CTX) ct[b * CTX + tt] = val;
  }
}

// ---------------- kernel 2: fused 2-layer context LSTM + head ----------------
__global__ void __launch_bounds__(256) ctx_lstm_kernel(
    const float* __restrict__ inp,
    const float* __restrict__ Wih0, const float* __restrict__ Whh0,
    const float* __restrict__ bih0, const float* __restrict__ bhh0,
    const float* __restrict__ Wih1, const float* __restrict__ Whh1,
    const float* __restrict__ bih1, const float* __restrict__ bhh1,
    const float* __restrict__ wdf, const float* __restrict__ bdfp,
    const float* __restrict__ wloc, const float* __restrict__ blocp,
    const float* __restrict__ wsc, const float* __restrict__ bscp,
    float* __restrict__ dfo, float* __restrict__ loco, float* __restrict__ sco,
    float* __restrict__ h0f, float* __restrict__ c0f,
    float* __restrict__ h1f, float* __restrict__ c1f)
{
  const int b = blockIdx.x, t = threadIdx.x;
  __shared__ float x_s[16], h0_s[64], h1_s[64], g_s[256];
  float wih0[15], whh0[64], wih1[64], whh1[64];
#pragma unroll
  for (int k = 0; k < 15; k++) wih0[k] = Wih0[t * 15 + k];
#pragma unroll
  for (int k = 0; k < 64; k++) whh0[k] = Whh0[t * 64 + k];
#pragma unroll
  for (int k = 0; k < 64; k++) wih1[k] = Wih1[t * 64 + k];
#pragma unroll
  for (int k = 0; k < 64; k++) whh1[k] = Whh1[t * 64 + k];
  const float bi0 = bih0[t], bh0 = bhh0[t], bi1 = bih1[t], bh1 = bhh1[t];
  const float bdf = bdfp[0], bloc = blocp[0], bsc = bscp[0];
  float wdfv = 0.f, wlocv = 0.f, wscv = 0.f;
  float c0 = 0.f, h0 = 0.f, c1 = 0.f, h1 = 0.f;
  if (t < 64) { h0_s[t] = 0.f; h1_s[t] = 0.f; wdfv = wdf[t]; wlocv = wloc[t]; wscv = wsc[t]; }
  __syncthreads();
  for (int tt = 0; tt < CTX; tt++) {
    if (t < 15) x_s[t] = inp[(size_t)(b * TM1 + tt) * NIN + t];
    __syncthreads();
    {
      float a = 0.f;
#pragma unroll
      for (int k = 0; k < 15; k++) a += wih0[k] * x_s[k];
      a += bi0;
      float a2 = 0.f;
#pragma unroll
      for (int k = 0; k < 64; k++) a2 += whh0[k] * h0_s[k];
      g_s[t] = (a + a2) + bh0;
    }
    __syncthreads();
    if (t < 64) {
      const float gi = g_s[t], gf = g_s[64 + t], gg = g_s[128 + t], go = g_s[192 + t];
      c0 = sigm(gf) * c0 + sigm(gi) * tanhf(gg);
      h0 = sigm(go) * tanhf(c0);
      h0_s[t] = h0;
    }
    __syncthreads();
    {
      float a = 0.f;
#pragma unroll
      for (int k = 0; k < 64; k++) a += wih1[k] * h0_s[k];
      a += bi1;
      float a2 = 0.f;
#pragma unroll
      for (int k = 0; k < 64; k++) a2 += whh1[k] * h1_s[k];
      g_s[t] = (a + a2) + bh1;
    }
    __syncthreads();
    if (t < 64) {
      const float gi = g_s[t], gf = g_s[64 + t], gg = g_s[128 + t], go = g_s[192 + t];
      c1 = sigm(gf) * c1 + sigm(gi) * tanhf(gg);
      h1 = sigm(go) * tanhf(c1);
      h1_s[t] = h1;
      float pd = h1 * wdfv, pl = h1 * wlocv, ps = h1 * wscv;
#pragma unroll
      for (int off = 32; off > 0; off >>= 1) {
        pd += __shfl_down(pd, off, 64);
        pl += __shfl_down(pl, off, 64);
        ps += __shfl_down(ps, off, 64);
      }
      if (t == 0) {
        dfo[b * CTX + tt]  = 2.0f + softplusf(pd + bdf);
        loco[b * CTX + tt] = pl + bloc;
        sco[b * CTX + tt]  = softplusf(ps + bsc);
      }
    }
    __syncthreads();
  }
  if (t < 64) { h0f[b * 64 + t] = h0; c0f[b * 64 + t] = c0; h1f[b * 64 + t] = h1; c1f[b * 64 + t] = c1; }
}

// ---------------- kernel 3: context sampling (y_ctx) ----------------
__global__ void __launch_bounds__(256) ctx_sample_kernel(
    const float* __restrict__ df, const float* __restrict__ loc, const float* __restrict__ sc,
    const float* __restrict__ tscale, float* __restrict__ yhat,
    u32 kz0, u32 kz1, u32 kg0, u32 kg1)
{
  const int i = blockIdx.x * 256 + threadIdx.x;
  const int r = i / CTX, t = i - r * CTX;
  const int b = r / NSAMP;
  const float dfv = df[b * CTX + t], lv = loc[b * CTX + t], sv = sc[b * CTX + t];
  const float z = normal_from_bits(jx_bits(kz0, kz1, NCTXS, (u32)i));
  u32 gk0, gk1;
  jx_subkey(kg0, kg1, NCTXS, (u32)i, gk0, gk1);
  const float g = jax_gamma_one(gk0, gk1, dfv * 0.5f);
  const float y = (lv + sv * (z * sqrtf(dfv / (2.0f * g)))) * tscale[b];
  yhat[(size_t)r * TM1 + t] = y;
}

// ---------------- kernel 5: persistent decode, K-quarter split ----------------
// 1600 blocks x 16 rows x 1024 threads. Thread = (gate g, K-quarter q) with
// q = lane&3 so a gate's 4 partials reduce via shfl_xor inside one wave.
// Per-thread live set ~95 VGPRs (52 weight floats) -> spill-free at the
// allocator's observed 128 cap. Elementwise phases: wave w = row, lane = unit,
// c0/c1 one register each.
__global__ void __launch_bounds__(1024) dec_persist_kernel(
    const float* __restrict__ inp, const float* __restrict__ tscale,
    const float* __restrict__ Wih0, const float* __restrict__ Whh0,
    const float* __restrict__ bih0, const float* __restrict__ bhh0,
    const float* __restrict__ Wih1, const float* __restrict__ Whh1,
    const float* __restrict__ bih1, const float* __restrict__ bhh1,
    const float* __restrict__ wdf, const float* __restrict__ bdfp,
    const float* __restrict__ wloc, const float* __restrict__ blocp,
    const float* __restrict__ wsc, const float* __restrict__ bscp,
    const float* __restrict__ h0f, const float* __restrict__ c0f,
    const float* __restrict__ h1f, const float* __restrict__ c1f,
    const float* __restrict__ ct, float* __restrict__ yhat,
    u32 kl0, u32 kl1)
{
  const int t    = threadIdx.x;
  const int lane = t & 63;
  const int w    = t >> 6;                 // wave 0..15 (= row in elementwise)
  const int q    = lane & 3;               // K-quarter
  const int gidx = (w << 4) | (lane >> 2); // gate 0..255

  __shared__ __align__(16) float h0s[DROWS][64];
  __shared__ __align__(16) float h1s[DROWS][64];
  __shared__ __align__(16) float hist[DROWS][64];   // lag ring
  __shared__ __align__(16) float g_s[DROWS][256];
  __shared__ __align__(16) float xs[DROWS][16];
  __shared__ float bsum[8][64];            // bih+bhh per layer/gate-slot
  __shared__ float hw3[3][64];             // head weights
  __shared__ float prevs[DROWS], tsr[DROWS];
  __shared__ float dfL[DROWS], locL[DROWS], scL[DROWS];

  const int base = blockIdx.x * DROWS;

  // ---- per-thread weights: K-quarter split (52 floats) ----
  float wih0q[4], whh0q[16], wih1q[16], whh1q[16];
#pragma unroll
  for (int k = 0; k < 4; k++) {
    const int kk = q * 4 + k;
    wih0q[k] = (kk < 15) ? Wih0[gidx * 15 + kk] : 0.0f;
  }
  {
    const float4* W = (const float4*)(Whh0 + gidx * 64 + q * 16);
#pragma unroll
    for (int k = 0; k < 4; k++) { float4 v = W[k]; whh0q[4*k]=v.x; whh0q[4*k+1]=v.y; whh0q[4*k+2]=v.z; whh0q[4*k+3]=v.w; }
  }
  {
    const float4* W = (const float4*)(Wih1 + gidx * 64 + q * 16);
#pragma unroll
    for (int k = 0; k < 4; k++) { float4 v = W[k]; wih1q[4*k]=v.x; wih1q[4*k+1]=v.y; wih1q[4*k+2]=v.z; wih1q[4*k+3]=v.w; }
  }
  {
    const float4* W = (const float4*)(Whh1 + gidx * 64 + q * 16);
#pragma unroll
    for (int k = 0; k < 4; k++) { float4 v = W[k]; whh1q[4*k]=v.x; whh1q[4*k+1]=v.y; whh1q[4*k+2]=v.z; whh1q[4*k+3]=v.w; }
  }
  const float bdf = bdfp[0], bloc = blocp[0], bsc = bscp[0];

  // ---- LDS init ----
  {
    const int bb = (base + w) / NSAMP;
    h0s[w][lane] = h0f[bb * 64 + lane];
    h1s[w][lane] = h1f[bb * 64 + lane];
  }
  if (t < DROWS * 28) {
    const int i = t / 28, k = t - i * 28;
    const int bb = (base + i) / NSAMP;
    hist[i][63 - k] = ct[bb * CTX + 335 - k];
  }
  if (t < 512) {
    const int m = t >> 6;
    bsum[m][lane] = (m < 4) ? (bih0[m * 64 + lane] + bhh0[m * 64 + lane])
                            : (bih1[(m - 4) * 64 + lane] + bhh1[(m - 4) * 64 + lane]);
  }
  if (t >= 512 && t < 704) {
    const int m = (t - 512) >> 6;
    hw3[m][lane] = (m == 0 ? wdf : (m == 1 ? wloc : wsc))[lane];
  }
  if (t >= 704 && t < 704 + DROWS) {
    const int i = t - 704;
    const int rg = base + i;
    prevs[i] = yhat[(size_t)rg * TM1 + 335];
    tsr[i] = tscale[rg / NSAMP];
  }
  float c0v, c1v;
  {
    const int bb = (base + w) / NSAMP;
    c0v = c0f[bb * 64 + lane];
    c1v = c1f[bb * 64 + lane];
  }
  __syncthreads();

  // ---- step loop ----
  for (int s = 0; s < NSTEP; s++) {
    // phase X: stage per-row inputs (16 rows x 16 feats)
    if (t < DROWS * 16) {
      const int i = t >> 4, f = t & 15;
      const int bb = (base + i) / NSAMP;
      if (f == 0) {
        const float nsv = prevs[i] / tsr[i];
        xs[i][0] = nsv;
        hist[i][s & 63] = nsv;
      } else if (f <= 10) {
        xs[i][f] = hist[i][(s - c_LAGS[f - 1]) & 63];
      } else if (f < 15) {
        xs[i][f] = inp[((size_t)bb * TM1 + CTX + s) * NIN + f];
      } else {
        xs[i][15] = 0.0f;
      }
    }
    __syncthreads();

    // phase G0: layer-0 gate partials (all 16 rows, two batches of 8)
#pragma unroll
    for (int r0 = 0; r0 < DROWS; r0 += 8) {
      float acc[8];
#pragma unroll
      for (int rr = 0; rr < 8; rr++) {
        const int row = r0 + rr;
        float a = 0.f;
        const float* xp = &xs[row][q * 4];
#pragma unroll
        for (int k = 0; k < 4; k++) a += wih0q[k] * xp[k];
        const float4* hp = (const float4*)&h0s[row][q * 16];
#pragma unroll
        for (int k = 0; k < 4; k++) {
          float4 v = hp[k];
          a += whh0q[4*k]*v.x; a += whh0q[4*k+1]*v.y; a += whh0q[4*k+2]*v.z; a += whh0q[4*k+3]*v.w;
        }
        acc[rr] = a;
      }
#pragma unroll
      for (int rr = 0; rr < 8; rr++) {
        float a = acc[rr];
        a += __shfl_xor(a, 1, 64);
        a += __shfl_xor(a, 2, 64);
        if (q == 0) g_s[r0 + rr][gidx] = a;
      }
    }
    __syncthreads();

    // phase C: layer-0 elementwise (wave w = row, lane = unit)
    {
      const float gi = g_s[w][lane]        + bsum[0][lane];
      const float gf = g_s[w][64 + lane]   + bsum[1][lane];
      const float gg = g_s[w][128 + lane]  + bsum[2][lane];
      const float go = g_s[w][192 + lane]  + bsum[3][lane];
      c0v = sigm(gf) * c0v + sigm(gi) * tanhf(gg);
      h0s[w][lane] = sigm(go) * tanhf(c0v);
    }
    __syncthreads();

    // phase G1: layer-1 gate partials
#pragma unroll
    for (int r0 = 0; r0 < DROWS; r0 += 8) {
      float acc[8];
#pragma unroll
      for (int rr = 0; rr < 8; rr++) {
        const int row = r0 + rr;
        float a = 0.f;
        const float4* hp = (const float4*)&h0s[row][q * 16];
#pragma unroll
        for (int k = 0; k < 4; k++) {
          float4 v = hp[k];
          a += wih1q[4*k]*v.x; a += wih1q[4*k+1]*v.y; a += wih1q[4*k+2]*v.z; a += wih1q[4*k+3]*v.w;
        }
        const float4* qp = (const float4*)&h1s[row][q * 16];
#pragma unroll
        for (int k = 0; k < 4; k++) {
          float4 v = qp[k];
          a += whh1q[4*k]*v.x; a += whh1q[4*k+1]*v.y; a += whh1q[4*k+2]*v.z; a += whh1q[4*k+3]*v.w;
        }
        acc[rr] = a;
      }
#pragma unroll
      for (int rr = 0; rr < 8; rr++) {
        float a = acc[rr];
        a += __shfl_xor(a, 1, 64);
        a += __shfl_xor(a, 2, 64);
        if (q == 0) g_s[r0 + rr][gidx] = a;
      }
    }
    __syncthreads();

    // phase E: layer-1 elementwise + head
    {
      const float gi = g_s[w][lane]        + bsum[4][lane];
      const float gf = g_s[w][64 + lane]   + bsum[5][lane];
      const float gg = g_s[w][128 + lane]  + bsum[6][lane];
      const float go = g_s[w][192 + lane]  + bsum[7][lane];
      c1v = sigm(gf) * c1v + sigm(gi) * tanhf(gg);
      const float h1v = sigm(go) * tanhf(c1v);
      h1s[w][lane] = h1v;
      float pd = h1v * hw3[0][lane], pl = h1v * hw3[1][lane], ps = h1v * hw3[2][lane];
#pragma unroll
      for (int off = 32; off > 0; off >>= 1) {
        pd += __shfl_down(pd, off, 64);
        pl += __shfl_down(pl, off, 64);
        ps += __shfl_down(ps, off, 64);
      }
      if (lane == 0) {
        dfL[w]  = 2.0f + softplusf(pd + bdf);
        locL[w] = pl + bloc;
        scL[w]  = softplusf(ps + bsc);
      }
    }
    __syncthreads();

    // phase S: sampling (16 rows)
    if (t < DROWS) {
      const int row = t, rg = base + row;
      u32 ks0, ks1, skz0, skz1, skg0, skg1;
      tf2x32(kl0, kl1, 0u, (u32)s, ks0, ks1);
      tf2x32(ks0, ks1, 0u, 0u, skz0, skz1);
      tf2x32(ks0, ks1, 0u, 1u, skg0, skg1);
      const float dfv = dfL[row], lv = locL[row], scv = scL[row];
      const float z = normal_from_bits(jx_bits(skz0, skz1, RTOT, (u32)rg));
      u32 gk0, gk1;
      jx_subkey(skg0, skg1, RTOT, (u32)rg, gk0, gk1);
      const float gam = jax_gamma_one(gk0, gk1, dfv * 0.5f);
      const float y = (lv + scv * (z * sqrtf(dfv / (2.0f * gam)))) * tsr[row];
      yhat[(size_t)rg * TM1 + CTX + s] = y;
      prevs[row] = y;
    }
    __syncthreads();
  }
}

// ---------------- kernel 6: median over 100 samples per (b,t) ----------------
__global__ void __launch_bounds__(256) median_kernel(
    const float* __restrict__ yhat, float* __restrict__ out)
{
  __shared__ float vals[4][100];
  const int wave = threadIdx.x >> 6, lane = threadIdx.x & 63;
  const int cell = blockIdx.x * 4 + wave;
  const int b = cell / TM1, t = cell - b * TM1;
  const float* basep = yhat + (size_t)b * NSAMP * TM1 + t;
  const float v1 = basep[(size_t)lane * TM1];
  vals[wave][lane] = v1;
  float v2 = 0.f;
  if (lane < 36) { v2 = basep[(size_t)(64 + lane) * TM1]; vals[wave][64 + lane] = v2; }
  __syncthreads();
  int cl1 = 0, ce1 = 0, cl2 = 0, ce2 = 0;
  for (int jj = 0; jj < 100; jj++) {
    const float w = vals[wave][jj];
    cl1 += (w < v1); ce1 += (w == v1);
    cl2 += (w < v2); ce2 += (w == v2);
  }
  if (cl1 <= 49 && 49 < cl1 + ce1) out[cell] = v1;
  if (lane < 36 && cl2 <= 49 && 49 < cl2 + ce2) out[cell] = v2;
}

// ---------------- launch ----------------
extern "C" void kernel_launch(void* const* d_in, const int* in_sizes, int n_in,
                              void* d_out, int out_size, void* d_ws, size_t ws_size,
                              hipStream_t stream) {
  (void)in_sizes; (void)n_in; (void)out_size; (void)ws_size;
  const float* X     = (const float*)d_in[0];
  const float* Wih0  = (const float*)d_in[2];
  const float* Whh0  = (const float*)d_in[3];
  const float* bih0  = (const float*)d_in[4];
  const float* bhh0  = (const float*)d_in[5];
  const float* Wih1  = (const float*)d_in[6];
  const float* Whh1  = (const float*)d_in[7];
  const float* bih1  = (const float*)d_in[8];
  const float* bhh1  = (const float*)d_in[9];
  const float* wdf   = (const float*)d_in[10];
  const float* bdf   = (const float*)d_in[11];
  const float* wloc  = (const float*)d_in[12];
  const float* bloc  = (const float*)d_in[13];
  const float* wsc   = (const float*)d_in[14];
  const float* bsc   = (const float*)d_in[15];
  const float* emb   = (const float*)d_in[16];

  float* wsf = (float*)d_ws;
  float* inp  = wsf + OFF_INP;
  float* ct   = wsf + OFF_CT;
  float* ts   = wsf + OFF_TS;
  float* lts  = wsf + OFF_LTS;
  float* dfp  = wsf + OFF_DF;
  float* locp = wsf + OFF_LOC;
  float* scp  = wsf + OFF_SC;
  float* h0f  = wsf + OFF_H0F;
  float* c0f  = wsf + OFF_C0F;
  float* h1f  = wsf + OFF_H1F;
  float* c1f  = wsf + OFF_C1F;
  float* yhat = wsf + OFF_YH;

  const u32 key0 = 0u, key1 = 42u;
  u32 kc0, kc1, kl0, kl1;
  jx_subkey(key0, key1, 2u, 0u, kc0, kc1);
  jx_subkey(key0, key1, 2u, 1u, kl0, kl1);
  u32 kz0, kz1, kg0, kg1;
  jx_subkey(kc0, kc1, 2u, 0u, kz0, kz1);
  jx_subkey(kc0, kc1, 2u, 1u, kg0, kg1);

  prep_kernel<<<NB, 256, 0, stream>>>(X, emb, inp, ct, ts, lts);
  ctx_lstm_kernel<<<NB, 256, 0, stream>>>(inp, Wih0, Whh0, bih0, bhh0, Wih1, Whh1, bih1, bhh1,
                                          wdf, bdf, wloc, bloc, wsc, bsc,
                                          dfp, locp, scp, h0f, c0f, h1f, c1f);
  ctx_sample_kernel<<<NCTXS / 256, 256, 0, stream>>>(dfp, locp, scp, ts, yhat, kz0, kz1, kg0, kg1);
  dec_persist_kernel<<<DBLOCKS, 1024, 0, stream>>>(inp, ts, Wih0, Whh0, bih0, bhh0,
                                                   Wih1, Whh1, bih1, bhh1,
                                                   wdf, bdf, wloc, bloc, wsc, bsc,
                                                   h0f, c0f, h1f, c1f, ct, yhat, kl0, kl1);
  median_kernel<<<(NB * TM1) / 4, 256, 0, stream>>>(yhat, (float*)d_out);
}